// Round 2
// baseline (32018.820 us; speedup 1.0000x reference)
//
#include <hip/hip_runtime.h>
#include <cmath>

constexpr int NB = 128;     // batch
constexpr int NS = 384;     // seq len
constexpr int NH = 384;     // hidden = input dim
constexpr int NZCOL = 3456; // 4H (gate p) + H (mv) + 4H (gate q)
constexpr int NG4 = 1536;

__device__ __forceinline__ double clampd(double x, double lo, double hi){ return fmin(fmax(x,lo),hi); }
__device__ __forceinline__ double artanh_(double x){ return atanh(clampd(x, -1.0 + 1e-7, 1.0 - 1e-7)); }
__device__ __forceinline__ double normclip(double s){ return sqrt(fmax(s, 1e-15)); }
__device__ __forceinline__ double wredsumd(double v){
  #pragma unroll
  for (int off = 32; off; off >>= 1) v += __shfl_xor(v, off, 64);
  return v;
}

// ---------------- zero doubles ----------------
__global__ void kzerod(double* p, int n){
  int i = blockIdx.x * 256 + threadIdx.x;
  if (i < n) p[i] = 0.0;
}

// ---------------- pack weights: WT[c][j] ----------------
// j in [0,1536): gates from W_all; [1536,1920): W_d; [1920,3456): U_all
__global__ void kprep(const float* __restrict__ W_all, const float* __restrict__ W_d,
                      const float* __restrict__ U_all, float* __restrict__ WT)
{
  int i = blockIdx.x * 256 + threadIdx.x;
  const int nWT = NH * NZCOL;
  if (i >= nWT) return;
  int c = i / NZCOL, j = i % NZCOL;
  float v;
  if (j < NG4){ int g = j / NH, r = j % NH; v = W_all[r * 1536 + g * NH + c]; }
  else if (j < 1920){ int r = j - NG4; v = W_d[r * NH + c]; }
  else { int jj = j - 1920; int g = jj / NH, r = jj % NH; v = U_all[(g * NH + r) * NH + c]; }
  WT[i] = v;
}

// ---------------- per-step GEMM (fp64 accumulate): z[b][j] = sum_c a[b][c] * WT[c][j] ----
// grid (27,4), block 256. N-tile 128 (boundaries 1536/1920 are multiples of 128), M-tile 32.
__global__ __launch_bounds__(256) void kgemm(const float* __restrict__ WT,
    const double* __restrict__ Hs, const double* __restrict__ CCs,
    const float* __restrict__ xin, double* __restrict__ Z, int t)
{
  int jb = blockIdx.x, mb = blockIdx.y;
  int j0 = jb * 128;
  __shared__ double at[32][33];
  int tid = threadIdx.x;
  int tx = tid & 31, ty = tid >> 5;
  int lm = tid >> 3;            // 0..31 staging row
  int lc = (tid & 7) * 4;       // c offset
  int gm = mb * 32 + lm;
  double acc[4][4] = {{0.0}};
  for (int c0 = 0; c0 < NH; c0 += 32){
    if (j0 >= 1920){
      const float* arow = xin + ((size_t)gm * NS + t) * NH;
      float4 a4 = *(const float4*)(arow + c0 + lc);
      at[lm][lc] = a4.x; at[lm][lc+1] = a4.y; at[lm][lc+2] = a4.z; at[lm][lc+3] = a4.w;
    } else {
      const double* arow = ((j0 < NG4) ? Hs : CCs) + (size_t)gm * NH;
      double2 a0 = *(const double2*)(arow + c0 + lc);
      double2 a1 = *(const double2*)(arow + c0 + lc + 2);
      at[lm][lc] = a0.x; at[lm][lc+1] = a0.y; at[lm][lc+2] = a1.x; at[lm][lc+3] = a1.y;
    }
    __syncthreads();
    const float* wp = WT + (size_t)c0 * NZCOL + j0 + tx * 4;
    #pragma unroll 4
    for (int c = 0; c < 32; ++c){
      float4 w4 = *(const float4*)(wp + (size_t)c * NZCOL);
      double w0 = w4.x, w1 = w4.y, w2 = w4.z, w3 = w4.w;
      #pragma unroll
      for (int mm = 0; mm < 4; ++mm){
        double a = at[ty * 4 + mm][c];
        acc[mm][0] += a * w0; acc[mm][1] += a * w1;
        acc[mm][2] += a * w2; acc[mm][3] += a * w3;
      }
    }
    __syncthreads();
  }
  int m0 = mb * 32 + ty * 4;
  #pragma unroll
  for (int mm = 0; mm < 4; ++mm){
    double* zp = Z + (size_t)(m0 + mm) * NZCOL + j0 + tx * 4;
    double2 o1; o1.x = acc[mm][0]; o1.y = acc[mm][1];
    double2 o2; o2.x = acc[mm][2]; o2.y = acc[mm][3];
    *(double2*)zp = o1; *(double2*)(zp + 2) = o2;
  }
}

// ---------------- per-step nonlinear (fp64): one wave per batch row ----------------
__global__ __launch_bounds__(256) void knl(const double* __restrict__ Z,
    double* __restrict__ Hs, double* __restrict__ CCs, float* __restrict__ ctx,
    const float* __restrict__ xin, const float* __restrict__ tstamps, int t)
{
  int wv = threadIdx.x >> 6, ln = threadIdx.x & 63;
  int b = blockIdx.x * 4 + wv;
  const double* zb = Z + (size_t)b * NZCOL;
  double ts = (double)tstamps[b * NS + t];

  double cc6[6], mv6[6];
  double s_cc = 0, s_h = 0, s_mv = 0, s_x = 0;
  #pragma unroll
  for (int i = 0; i < 6; ++i){
    int r = ln + 64 * i;
    double c_ = CCs[b * NH + r]; cc6[i] = c_; s_cc += c_ * c_;
    double h_ = Hs[b * NH + r];  s_h += h_ * h_;
    double m_ = zb[NG4 + r];     mv6[i] = m_; s_mv += m_ * m_;
    double x_ = (double)xin[((size_t)b * NS + t) * NH + r]; s_x += x_ * x_;
  }
  double cc2 = wredsumd(s_cc);  double cn = normclip(cc2);
  double h2  = wredsumd(s_h);   double hn = normclip(h2);
  double mv2 = wredsumd(s_mv);  double mvn = normclip(mv2);
  double x2s = wredsumd(s_x);   double xn = normclip(x2s);

  // ---- c path: c_s1 = expmap0(tanh(logmap0(mobius_matvec(W_d, cc)))) ----
  double s1 = tanh(mvn / cn * artanh_(cn));
  double m1[6]; double sm1 = 0;
  #pragma unroll
  for (int i = 0; i < 6; ++i){ m1[i] = s1 * mv6[i] / mvn; sm1 += m1[i] * m1[i]; }
  double n1 = normclip(wredsumd(sm1));
  double l1s = artanh_(n1) / n1;
  double v6[6]; double sv = 0;
  #pragma unroll
  for (int i = 0; i < 6; ++i){ v6[i] = tanh(l1s * m1[i]); sv += v6[i] * v6[i]; }
  double nv = normclip(wredsumd(sv));
  double e1 = tanh(nv) / nv;
  double cs1[6]; double scs = 0, sccd = 0;
  #pragma unroll
  for (int i = 0; i < 6; ++i){ cs1[i] = e1 * v6[i]; scs += cs1[i] * cs1[i]; sccd += (-cs1[i]) * cc6[i]; }

  // c_s2 = mobius_pw(c_s1, t_s * ones)
  double xnt = sqrt(fmax(384.0 * ts * ts, 1e-15));
  double swx = 0;
  #pragma unroll
  for (int i = 0; i < 6; ++i){ double w = cs1[i] * ts; swx += w * w; }
  double wxn1 = normclip(wredsumd(swx));
  double s2c = tanh(wxn1 / xnt * artanh_(xnt)) / wxn1;
  double cs2[6];
  #pragma unroll
  for (int i = 0; i < 6; ++i) cs2[i] = s2c * (cs1[i] * ts);

  // A = mobius_add(-c_s1, cc)
  double x2a = wredsumd(scs);
  double xya = wredsumd(sccd);
  double y2a = cc2;
  double cXA = 1.0 + 2.0 * xya + y2a, cYA = 1.0 - x2a;
  double dA = fmax(1.0 + 2.0 * xya + x2a * y2a, 1e-15);
  double A6[6]; double sA = 0, sAc = 0, sc2 = 0;
  #pragma unroll
  for (int i = 0; i < 6; ++i){
    A6[i] = (cXA * (-cs1[i]) + cYA * cc6[i]) / dA;
    sA += A6[i] * A6[i]; sAc += A6[i] * cs2[i]; sc2 += cs2[i] * cs2[i];
  }
  // c_adj = mobius_add(A, c_s2)
  double x2b = wredsumd(sA), xyb = wredsumd(sAc), y2b = wredsumd(sc2);
  double cXB = 1.0 + 2.0 * xyb + y2b, cYB = 1.0 - x2b;
  double dB = fmax(1.0 + 2.0 * xyb + x2b * y2b, 1e-15);
  double cadj[6];
  #pragma unroll
  for (int i = 0; i < 6; ++i) cadj[i] = (cXB * A6[i] + cYB * cs2[i]) / dB;

  // ---- gates f,i,o,ct (load p/q per gate from Z to limit registers) ----
  double art_hn = artanh_(hn), art_xn = artanh_(xn);
  double gates[4][6];
  for (int g = 0; g < 4; ++g){
    double pg[6], qg[6]; double s_p = 0, s_q = 0;
    #pragma unroll
    for (int i = 0; i < 6; ++i){
      int r = ln + 64 * i;
      pg[i] = zb[g * NH + r];        s_p += pg[i] * pg[i];
      qg[i] = zb[1920 + g * NH + r]; s_q += qg[i] * qg[i];
    }
    double pn = normclip(wredsumd(s_p));
    double qn = normclip(wredsumd(s_q));
    double sa = tanh(pn / hn * art_hn) / pn;
    double sb = tanh(qn / xn * art_xn) / qn;
    double a6[6], b6[6]; double sx2 = 0, sy2 = 0, sxy = 0;
    #pragma unroll
    for (int i = 0; i < 6; ++i){
      a6[i] = sa * pg[i]; b6[i] = sb * qg[i];
      sx2 += a6[i] * a6[i]; sy2 += b6[i] * b6[i]; sxy += a6[i] * b6[i];
    }
    sx2 = wredsumd(sx2); sy2 = wredsumd(sy2); sxy = wredsumd(sxy);
    double cX = 1.0 + 2.0 * sxy + sy2, cY = 1.0 - sx2;
    double dd = fmax(1.0 + 2.0 * sxy + sx2 * sy2, 1e-15);
    double m6[6]; double smm = 0;
    #pragma unroll
    for (int i = 0; i < 6; ++i){ m6[i] = (cX * a6[i] + cY * b6[i]) / dd; smm += m6[i] * m6[i]; }
    double nm = normclip(wredsumd(smm));
    double sl = artanh_(nm) / nm;
    #pragma unroll
    for (int i = 0; i < 6; ++i) gates[g][i] = 1.0 / (1.0 + exp(-sl * m6[i]));
  }

  // ---- cc_n = mobius_add(pw(i,ct), pw(f,c_adj)) ----
  double sct = 0, sict = 0; double wP[6];
  #pragma unroll
  for (int i = 0; i < 6; ++i){ double ct = gates[3][i]; sct += ct * ct; wP[i] = gates[1][i] * ct; sict += wP[i] * wP[i]; }
  double ctn = normclip(wredsumd(sct));
  double wPn = normclip(wredsumd(sict));
  double sP = tanh(wPn / ctn * artanh_(ctn)) / wPn;
  double P6[6]; double sPP = 0;
  #pragma unroll
  for (int i = 0; i < 6; ++i){ P6[i] = sP * wP[i]; sPP += P6[i] * P6[i]; }
  double sca = 0, sfca = 0; double wQ[6];
  #pragma unroll
  for (int i = 0; i < 6; ++i){ sca += cadj[i] * cadj[i]; wQ[i] = gates[0][i] * cadj[i]; sfca += wQ[i] * wQ[i]; }
  double can = normclip(wredsumd(sca));
  double wQn = normclip(wredsumd(sfca));
  double sQ = tanh(wQn / can * artanh_(can)) / wQn;
  double Q6[6]; double sQQ = 0, sPQ = 0;
  #pragma unroll
  for (int i = 0; i < 6; ++i){ Q6[i] = sQ * wQ[i]; sQQ += Q6[i] * Q6[i]; sPQ += P6[i] * Q6[i]; }
  double x2c = wredsumd(sPP), y2c = wredsumd(sQQ), xyc = wredsumd(sPQ);
  double cXC = 1.0 + 2.0 * xyc + y2c, cYC = 1.0 - x2c;
  double dC = fmax(1.0 + 2.0 * xyc + x2c * y2c, 1e-15);
  double ccn6[6], w6[6]; double sw_ = 0;
  #pragma unroll
  for (int i = 0; i < 6; ++i){ ccn6[i] = (cXC * P6[i] + cYC * Q6[i]) / dC; w6[i] = tanh(ccn6[i]); sw_ += w6[i] * w6[i]; }
  double nw = normclip(wredsumd(sw_));
  double ee = tanh(nw) / nw;
  double e6[6], wH[6]; double se = 0, soe = 0;
  #pragma unroll
  for (int i = 0; i < 6; ++i){ e6[i] = ee * w6[i]; se += e6[i] * e6[i]; wH[i] = gates[2][i] * e6[i]; soe += wH[i] * wH[i]; }
  double en = normclip(wredsumd(se));
  double wHn = normclip(wredsumd(soe));
  double sH = tanh(wHn / en * artanh_(en)) / wHn;
  #pragma unroll
  for (int i = 0; i < 6; ++i){
    int r = ln + 64 * i;
    CCs[b * NH + r] = ccn6[i];
    Hs[b * NH + r] = sH * wH[i];
    ctx[((size_t)b * NS + t) * NH + r] = (float)gates[2][i];
  }
}

// ---------------- block reduce helpers (256 threads / 4 waves), double ----------------
__device__ __forceinline__ double blocksumd(double v, double* red){
  v = wredsumd(v);
  __syncthreads();
  if ((threadIdx.x & 63) == 0) red[threadIdx.x >> 6] = v;
  __syncthreads();
  return red[0] + red[1] + red[2] + red[3];
}
__device__ __forceinline__ double blockmaxd(double v, double* red){
  #pragma unroll
  for (int off = 32; off; off >>= 1) v = fmax(v, __shfl_xor(v, off, 64));
  __syncthreads();
  if ((threadIdx.x & 63) == 0) red[threadIdx.x >> 6] = v;
  __syncthreads();
  return fmax(fmax(red[0], red[1]), fmax(red[2], red[3]));
}

// ---------------- query / scores / softmax / aw / bt (one block per b) ----------------
__global__ __launch_bounds__(256) void kattn1(const double* __restrict__ Hs,
    const float* __restrict__ Win, const float* __restrict__ ctx,
    const float* __restrict__ dt, const float* __restrict__ ab,
    double* __restrict__ query, double* __restrict__ aw, double* __restrict__ bt)
{
  int b = blockIdx.x; int tid = threadIdx.x;
  __shared__ double hL[NH], qL[NH], sc[NS];
  __shared__ double red[4];
  for (int r = tid; r < NH; r += 256) hL[r] = Hs[b * NH + r];
  __syncthreads();
  for (int r = tid; r < NH; r += 256){
    double s = 0;
    const float* wr = Win + (size_t)r * NH;
    for (int c = 0; c < NH; ++c) s += hL[c] * (double)wr[c];
    qL[r] = s; query[b * NH + r] = s;
  }
  __syncthreads();
  int wv = tid >> 6, ln = tid & 63;
  for (int s_ = wv; s_ < NS; s_ += 4){
    const float* crow = ctx + ((size_t)b * NS + s_) * NH;
    double par = 0;
    #pragma unroll
    for (int i = 0; i < 6; ++i){ int d = ln + 64 * i; par += qL[d] * (double)crow[d]; }
    par = wredsumd(par);
    if (ln == 0) sc[s_] = par;
  }
  __syncthreads();
  double v0 = sc[tid];
  double v1 = (tid + 256 < NS) ? sc[tid + 256] : -1e300;
  double mx = blockmaxd(fmax(v0, v1), red);
  double e0 = exp(v0 - mx);
  double e1 = (tid + 256 < NS) ? exp(v1 - mx) : 0.0;
  double tot = blocksumd(e0 + e1, red);
  double a0 = e0 / tot, a1 = e1 / tot;
  double n = normclip(blocksumd(a0 * a0 + a1 * a1, red));
  double s1 = tanh(n) / n;
  double w0 = s1 * a0, w1 = s1 * a1;
  double pn = normclip(blocksumd(w0 * w0 + w1 * w1, red));
  if (pn > 0.999){ double f = 0.999 / pn; w0 *= f; w1 *= f; }
  aw[b * NS + tid] = w0;
  if (tid + 256 < NS) aw[b * NS + tid + 256] = w1;
  // bt = project(expmap0(exp(-ab*delta_t)))
  double abv = (double)ab[b];
  double b0 = exp(-abv * (double)dt[b * NS + tid]);
  double b1v = (tid + 256 < NS) ? exp(-abv * (double)dt[b * NS + tid + 256]) : 0.0;
  double nb = normclip(blocksumd(b0 * b0 + b1v * b1v, red));
  double sb = tanh(nb) / nb;
  double c0 = sb * b0, c1 = sb * b1v;
  double pnb = normclip(blocksumd(c0 * c0 + c1 * c1, red));
  if (pnb > 0.999){ double f = 0.999 / pnb; c0 *= f; c1 *= f; }
  bt[b * NS + tid] = c0;
  if (tid + 256 < NS) bt[b * NS + tid + 256] = c1;
}

// ---------------- hyperbolic attention mixing, one block per (b, 32 h-rows) ----------------
__global__ __launch_bounds__(256) void kmix(const float* __restrict__ ctx,
    const double* __restrict__ aw, const double* __restrict__ bt,
    const float* __restrict__ ae, double* __restrict__ nom, double* __restrict__ den)
{
  int b = blockIdx.y; int h0 = blockIdx.x * 32;
  __shared__ float T[32][385];
  int tid = threadIdx.x;
  for (int idx = tid; idx < NS * 32; idx += 256){
    int s = idx >> 5, hh = idx & 31;
    T[hh][s] = ctx[((size_t)b * NS + s) * NH + h0 + hh];
  }
  __syncthreads();
  int wv = tid >> 6, ln = tid & 63;
  double aev = (double)ae[b];
  double aw6[6], bt6[6]; double sbt = 0;
  #pragma unroll
  for (int i = 0; i < 6; ++i){
    aw6[i] = aw[b * NS + ln + 64 * i];
    bt6[i] = bt[b * NS + ln + 64 * i];
    sbt += bt6[i] * bt6[i];
  }
  double xnb = normclip(wredsumd(sbt));
  double art_xnb = artanh_(xnb);
  double denacc = 0.0;
  for (int k = 0; k < 8; ++k){
    int hh = wv * 8 + k;
    double v[6]; double sx = 0;
    #pragma unroll
    for (int i = 0; i < 6; ++i){ v[i] = (double)T[hh][ln + 64 * i]; sx += v[i] * v[i]; }
    double xnv = normclip(wredsumd(sx));
    double wx[6]; double swx = 0;
    #pragma unroll
    for (int i = 0; i < 6; ++i){ wx[i] = aw6[i] * v[i]; swx += wx[i] * wx[i]; }
    double wxn = normclip(wredsumd(swx));
    double s1 = tanh(wxn / xnv * artanh_(xnv)) / wxn;
    double mix[6]; double sm = 0;
    #pragma unroll
    for (int i = 0; i < 6; ++i){ mix[i] = s1 * wx[i]; sm += mix[i] * mix[i]; }
    double n1 = normclip(wredsumd(sm));
    if (n1 > 0.999){ double f = 0.999 / n1;
      #pragma unroll
      for (int i = 0; i < 6; ++i) mix[i] *= f; }
    // tmp = project(pw(ae, mix))
    double sm2 = 0;
    #pragma unroll
    for (int i = 0; i < 6; ++i) sm2 += mix[i] * mix[i];
    double xn2 = normclip(wredsumd(sm2));
    double wx2[6]; double sw2 = 0;
    #pragma unroll
    for (int i = 0; i < 6; ++i){ wx2[i] = aev * mix[i]; sw2 += wx2[i] * wx2[i]; }
    double wxn2 = normclip(wredsumd(sw2));
    double s2 = tanh(wxn2 / xn2 * artanh_(xn2)) / wxn2;
    double tmp[6]; double st = 0;
    #pragma unroll
    for (int i = 0; i < 6; ++i){ tmp[i] = s2 * wx2[i]; st += tmp[i] * tmp[i]; }
    double n2 = normclip(wredsumd(st));
    if (n2 > 0.999){ double f = 0.999 / n2;
      #pragma unroll
      for (int i = 0; i < 6; ++i) tmp[i] *= f; }
    // tmp = project(pw(tmp, bt))
    double wx3[6]; double sw3 = 0;
    #pragma unroll
    for (int i = 0; i < 6; ++i){ wx3[i] = tmp[i] * bt6[i]; sw3 += wx3[i] * wx3[i]; }
    double wxn3 = normclip(wredsumd(sw3));
    double s3 = tanh(wxn3 / xnb * art_xnb) / wxn3;
    double t2[6]; double st2 = 0;
    #pragma unroll
    for (int i = 0; i < 6; ++i){ t2[i] = s3 * wx3[i]; st2 += t2[i] * t2[i]; }
    double n3 = normclip(wredsumd(st2));
    if (n3 > 0.999){ double f = 0.999 / n3;
      #pragma unroll
      for (int i = 0; i < 6; ++i) t2[i] *= f; }
    #pragma unroll
    for (int i = 0; i < 6; ++i) t2[i] = fmax(t2[i], 0.0);
    // mix = project(mobius_add(mix, relu(tmp)))
    double sxx = 0, syy = 0, sxy = 0;
    #pragma unroll
    for (int i = 0; i < 6; ++i){ sxx += mix[i] * mix[i]; syy += t2[i] * t2[i]; sxy += mix[i] * t2[i]; }
    sxx = wredsumd(sxx); syy = wredsumd(syy); sxy = wredsumd(sxy);
    double dn = fmax(1.0 + 2.0 * sxy + sxx * syy, 1e-15);
    double ca = (1.0 + 2.0 * sxy + syy) / dn, cb = (1.0 - sxx) / dn;
    double m2[6]; double sm3 = 0;
    #pragma unroll
    for (int i = 0; i < 6; ++i){ m2[i] = ca * mix[i] + cb * t2[i]; sm3 += m2[i] * m2[i]; }
    double n4 = normclip(wredsumd(sm3));
    if (n4 > 0.999){ double f = 0.999 / n4;
      #pragma unroll
      for (int i = 0; i < 6; ++i) m2[i] *= f; }
    double snn = 0;
    #pragma unroll
    for (int i = 0; i < 6; ++i) snn += m2[i] * m2[i];
    snn = wredsumd(snn);
    double lam = 2.0 / fmax(1.0 - snn, 1e-15);
    #pragma unroll
    for (int i = 0; i < 6; ++i) atomicAdd(&nom[b * NS + ln + 64 * i], lam * m2[i]);
    if (ln == 0) denacc += lam - 1.0;
  }
  if (ln == 0) atomicAdd(&den[b], denacc);
}

// ---------------- midpoint + logmap0 + output head, one block per b ----------------
__global__ __launch_bounds__(256) void kfinal(const double* __restrict__ nom,
    const double* __restrict__ den, const double* __restrict__ query,
    const float* __restrict__ Wout, const float* __restrict__ W1,
    const float* __restrict__ b1, const float* __restrict__ W2,
    const float* __restrict__ b2, float* __restrict__ out)
{
  int b = blockIdx.x; int tid = threadIdx.x;
  __shared__ double comb[768];
  __shared__ double att[NH];
  __shared__ double x1[NH];
  __shared__ double red[4];
  double dnb = fmax(den[b], 1e-10);
  double u0 = nom[b * NS + tid] / dnb;
  double u1 = (tid + 256 < NS) ? nom[b * NS + tid + 256] / dnb : 0.0;
  double n = normclip(blocksumd(u0 * u0 + u1 * u1, red));
  double sf = tanh(0.5 * artanh_(n)) / n;
  double f0 = sf * u0, f1 = sf * u1;
  double n2 = normclip(blocksumd(f0 * f0 + f1 * f1, red));
  double sl = artanh_(n2) / n2;
  comb[tid] = sl * f0;
  if (tid + 256 < NS) comb[tid + 256] = sl * f1;
  for (int r = tid; r < NH; r += 256) comb[NH + r] = query[b * NH + r];
  __syncthreads();
  for (int r = tid; r < NH; r += 256){
    double s = 0;
    const float* wr = Wout + (size_t)r * 768;
    for (int c = 0; c < 768; ++c) s += comb[c] * (double)wr[c];
    att[r] = tanh(s);
  }
  __syncthreads();
  for (int r = tid; r < NH; r += 256){
    double s = (double)b1[r];
    const float* wr = W1 + (size_t)r * NH;
    for (int c = 0; c < NH; ++c) s += att[c] * (double)wr[c];
    x1[r] = fmax(s, 0.0);
  }
  __syncthreads();
  double p0 = 0, p1 = 0;
  for (int c = tid; c < NH; c += 256){ p0 += x1[c] * (double)W2[c]; p1 += x1[c] * (double)W2[NH + c]; }
  p0 = blocksumd(p0, red);
  p1 = blocksumd(p1, red);
  if (tid == 0){ out[b * 2 + 0] = (float)(p0 + (double)b2[0]); out[b * 2 + 1] = (float)(p1 + (double)b2[1]); }
}

extern "C" void kernel_launch(void* const* d_in, const int* in_sizes, int n_in,
                              void* d_out, int out_size, void* d_ws, size_t ws_size,
                              hipStream_t stream)
{
  const float* inputs  = (const float*)d_in[0];
  const float* tstamps = (const float*)d_in[1];
  const float* delta_t = (const float*)d_in[2];
  const float* W_all   = (const float*)d_in[3];
  const float* U_all   = (const float*)d_in[4];
  const float* W_d     = (const float*)d_in[5];
  const float* Win     = (const float*)d_in[6];
  const float* Wout    = (const float*)d_in[7];
  const float* ae      = (const float*)d_in[8];
  const float* ab      = (const float*)d_in[9];
  const float* W1      = (const float*)d_in[10];
  const float* b1      = (const float*)d_in[11];
  const float* W2      = (const float*)d_in[12];
  const float* b2      = (const float*)d_in[13];
  float* out = (float*)d_out;

  // double region first (base is 256B aligned)
  double* wd = (double*)d_ws;
  size_t od = 0;
  double* HsD   = wd + od; od += (size_t)NB * NH;     // 49152
  double* CCsD  = wd + od; od += (size_t)NB * NH;     // 49152
  double* NOMD  = wd + od; od += (size_t)NB * NS;     // 49152
  double* DEND  = wd + od; od += (size_t)NB;          // 128
  double* ZD    = wd + od; od += (size_t)NB * NZCOL;  // 442368
  double* QUERY = wd + od; od += (size_t)NB * NH;
  double* AW    = wd + od; od += (size_t)NB * NS;
  double* BT    = wd + od; od += (size_t)NB * NS;
  float* wf = (float*)(wd + od);
  size_t of = 0;
  float* WT  = wf + of; of += (size_t)NH * NZCOL;     // 1,327,104
  float* CTX = wf + of; of += (size_t)NB * NS * NH;   // 18,874,368

  // zero Hs, CCs, NOM, DEN (contiguous doubles)
  int nz = NB * NH * 3 + NB;
  hipLaunchKernelGGL(kzerod, dim3((nz + 255) / 256), dim3(256), 0, stream, HsD, nz);

  int nprep = NH * NZCOL;
  hipLaunchKernelGGL(kprep, dim3((nprep + 255) / 256), dim3(256), 0, stream,
                     W_all, W_d, U_all, WT);

  for (int t = 0; t < NS; ++t){
    hipLaunchKernelGGL(kgemm, dim3(27, 4), dim3(256), 0, stream, WT, HsD, CCsD, inputs, ZD, t);
    hipLaunchKernelGGL(knl, dim3(32), dim3(256), 0, stream, ZD, HsD, CCsD, CTX, inputs, tstamps, t);
  }

  hipLaunchKernelGGL(kattn1, dim3(128), dim3(256), 0, stream,
                     HsD, Win, CTX, delta_t, ab, QUERY, AW, BT);
  hipLaunchKernelGGL(kmix, dim3(12, 128), dim3(256), 0, stream, CTX, AW, BT, ae, NOMD, DEND);
  hipLaunchKernelGGL(kfinal, dim3(128), dim3(256), 0, stream,
                     NOMD, DEND, QUERY, Wout, W1, b1, W2, b2, out);
}

// Round 3
// 19388.483 us; speedup vs baseline: 1.6514x; 1.6514x over previous
//
#include <hip/hip_runtime.h>
#include <cmath>

constexpr int NB = 128;     // batch
constexpr int NS = 384;     // seq len
constexpr int NH = 384;     // hidden = input dim
constexpr int NZCOL = 3456; // 4H (gate p) + H (mv) + 4H (gate q)
constexpr int NG4 = 1536;

__device__ __forceinline__ double clampd(double x, double lo, double hi){ return fmin(fmax(x,lo),hi); }
__device__ __forceinline__ double artanh_(double x){ return atanh(clampd(x, -1.0 + 1e-7, 1.0 - 1e-7)); }
__device__ __forceinline__ double normclip(double s){ return sqrt(fmax(s, 1e-15)); }
__device__ __forceinline__ double wredsumd(double v){
  #pragma unroll
  for (int off = 32; off; off >>= 1) v += __shfl_xor(v, off, 64);
  return v;
}

// ---------------- zero ----------------
__global__ void kzerod(double* p, int n){
  int i = blockIdx.x * 256 + threadIdx.x;
  if (i < n) p[i] = 0.0;
}
__global__ void kzerof(float* p, int n){
  int i = blockIdx.x * 256 + threadIdx.x;
  if (i < n) p[i] = 0.f;
}

// ---------------- pack weights: WT[c][j] ----------------
// j in [0,1536): gates from W_all; [1536,1920): W_d; [1920,3456): U_all
__global__ void kprep(const float* __restrict__ W_all, const float* __restrict__ W_d,
                      const float* __restrict__ U_all, float* __restrict__ WT)
{
  int i = blockIdx.x * 256 + threadIdx.x;
  const int nWT = NH * NZCOL;
  if (i >= nWT) return;
  int c = i / NZCOL, j = i % NZCOL;
  float v;
  if (j < NG4){ int g = j / NH, r = j % NH; v = W_all[r * 1536 + g * NH + c]; }
  else if (j < 1920){ int r = j - NG4; v = W_d[r * NH + c]; }
  else { int jj = j - 1920; int g = jj / NH, r = jj % NH; v = U_all[(g * NH + r) * NH + c]; }
  WT[i] = v;
}

// ---------------- one-time Q GEMM: Q[bs][j] = sum_c X[bs][c] * Bw[c][j] ----------------
// X = inputs [49152 x 384]; Bw = WT + 1920 (row stride 3456); Q [49152 x 1536]
// grid (24, 768), block 256; tile 64x64, K-chunk 32, thread 4x4; fp32 FMA + fp64 chunk-sum.
__global__ __launch_bounds__(256) void kqgemm(const float* __restrict__ X,
    const float* __restrict__ Bw, float* __restrict__ Q)
{
  int j0 = blockIdx.x * 64, i0 = blockIdx.y * 64;
  __shared__ float As[32][68];   // [k][m], stride 68 keeps float4 rows aligned
  __shared__ float Bs[32][64];   // [k][n]
  int tid = threadIdx.x;
  int tn = tid & 15, tm = tid >> 4;      // *4 each
  int slm = tid >> 2;                    // 0..63  A row
  int slc = (tid & 3) * 8;               // k offset (8 wide)
  int blk = tid >> 3;                    // 0..31  B k-row
  int bln = (tid & 7) * 8;               // n offset
  double accd[4][4] = {{0.0}};
  const float* arow = X + (size_t)(i0 + slm) * NH;
  for (int c0 = 0; c0 < NH; c0 += 32){
    float4 a4 = *(const float4*)(arow + c0 + slc);
    float4 a4b = *(const float4*)(arow + c0 + slc + 4);
    As[slc+0][slm] = a4.x;  As[slc+1][slm] = a4.y;
    As[slc+2][slm] = a4.z;  As[slc+3][slm] = a4.w;
    As[slc+4][slm] = a4b.x; As[slc+5][slm] = a4b.y;
    As[slc+6][slm] = a4b.z; As[slc+7][slm] = a4b.w;
    const float* bp = Bw + (size_t)(c0 + blk) * NZCOL + j0 + bln;
    float4 b4a = *(const float4*)bp;
    float4 b4b = *(const float4*)(bp + 4);
    *(float4*)&Bs[blk][bln] = b4a;
    *(float4*)&Bs[blk][bln+4] = b4b;
    __syncthreads();
    float acc[4][4] = {{0.f}};
    #pragma unroll 8
    for (int c = 0; c < 32; ++c){
      float4 av = *(const float4*)&As[c][tm*4];
      float4 bv = *(const float4*)&Bs[c][tn*4];
      float a[4] = {av.x, av.y, av.z, av.w};
      float bb[4] = {bv.x, bv.y, bv.z, bv.w};
      #pragma unroll
      for (int mm = 0; mm < 4; ++mm)
        #pragma unroll
        for (int jj = 0; jj < 4; ++jj)
          acc[mm][jj] += a[mm] * bb[jj];
    }
    __syncthreads();
    #pragma unroll
    for (int mm = 0; mm < 4; ++mm)
      #pragma unroll
      for (int jj = 0; jj < 4; ++jj) accd[mm][jj] += (double)acc[mm][jj];
  }
  #pragma unroll
  for (int mm = 0; mm < 4; ++mm){
    float4 o; o.x = (float)accd[mm][0]; o.y = (float)accd[mm][1];
    o.z = (float)accd[mm][2]; o.w = (float)accd[mm][3];
    *(float4*)(Q + (size_t)(i0 + tm*4 + mm) * 1536 + j0 + tn*4) = o;
  }
}

// ---------------- per-step GEMM: Z[b][j] = sum_c A[b][c] * WT[c][j] ----------------
// A selected by j-range: [0,1536) Hs; [1536,1920) CCs; [1920,3456) x_t (fallback only).
// grid (ncols/64, 4), block 256; tile M=32 N=64, K-chunk 32; fp32 FMA + fp64 chunk-sum.
__global__ __launch_bounds__(256) void kgemm(const float* __restrict__ WT,
    const float* __restrict__ Hs, const float* __restrict__ CCs,
    const float* __restrict__ xin, float* __restrict__ Z, int zstride, int t)
{
  int j0 = blockIdx.x * 64;
  int m0 = blockIdx.y * 32;
  __shared__ float As[32][36];   // [k][m]
  __shared__ float Bs[32][64];   // [k][n]
  int tid = threadIdx.x;
  int tn = tid & 15;             // *4 cols
  int tm = tid >> 4;             // 0..15, *2 rows
  int slm = tid >> 3;            // 0..31 A row
  int slc = (tid & 7) * 4;       // k offset
  int blk = tid >> 3;            // 0..31 B k-row
  int bln = (tid & 7) * 8;       // n offset
  double accd[2][4] = {{0.0}};
  int gm = m0 + slm;
  const float* arow;
  if (j0 < NG4)       arow = Hs  + (size_t)gm * NH;
  else if (j0 < 1920) arow = CCs + (size_t)gm * NH;
  else                arow = xin + ((size_t)gm * NS + t) * NH;
  for (int c0 = 0; c0 < NH; c0 += 32){
    float4 a4 = *(const float4*)(arow + c0 + slc);
    As[slc+0][slm] = a4.x; As[slc+1][slm] = a4.y;
    As[slc+2][slm] = a4.z; As[slc+3][slm] = a4.w;
    const float* bp = WT + (size_t)(c0 + blk) * NZCOL + j0 + bln;
    float4 b4a = *(const float4*)bp;
    float4 b4b = *(const float4*)(bp + 4);
    *(float4*)&Bs[blk][bln] = b4a;
    *(float4*)&Bs[blk][bln+4] = b4b;
    __syncthreads();
    float acc[2][4] = {{0.f}};
    #pragma unroll 8
    for (int c = 0; c < 32; ++c){
      float2 a2 = *(const float2*)&As[c][tm*2];
      float4 bv = *(const float4*)&Bs[c][tn*4];
      acc[0][0] += a2.x * bv.x; acc[0][1] += a2.x * bv.y;
      acc[0][2] += a2.x * bv.z; acc[0][3] += a2.x * bv.w;
      acc[1][0] += a2.y * bv.x; acc[1][1] += a2.y * bv.y;
      acc[1][2] += a2.y * bv.z; acc[1][3] += a2.y * bv.w;
    }
    __syncthreads();
    #pragma unroll
    for (int mm = 0; mm < 2; ++mm)
      #pragma unroll
      for (int jj = 0; jj < 4; ++jj) accd[mm][jj] += (double)acc[mm][jj];
  }
  #pragma unroll
  for (int mm = 0; mm < 2; ++mm){
    float4 o; o.x = (float)accd[mm][0]; o.y = (float)accd[mm][1];
    o.z = (float)accd[mm][2]; o.w = (float)accd[mm][3];
    *(float4*)(Z + (size_t)(m0 + tm*2 + mm) * zstride + j0 + tn*4) = o;
  }
}

// ---------------- per-step nonlinear: one wave per batch row ----------------
// fp32 vectors + fp32 vector transcendentals; fp64 norms/reductions/scalars (exact clamp).
__global__ __launch_bounds__(256) void knl(const float* __restrict__ Z, int zstride,
    const float* __restrict__ qsrc, unsigned long long q_bs, unsigned long long q_ts,
    float* __restrict__ Hs, float* __restrict__ CCs, float* __restrict__ ctx,
    const float* __restrict__ xin, const float* __restrict__ tstamps, int t)
{
  int wv = threadIdx.x >> 6, ln = threadIdx.x & 63;
  int b = blockIdx.x * 4 + wv;
  const float* zb = Z + (size_t)b * zstride;
  const float* qb = qsrc + (size_t)b * q_bs + (size_t)t * q_ts;
  double ts = (double)tstamps[b * NS + t];
  float tsf = (float)ts;

  float cc6[6], mv6[6];
  double s_cc = 0, s_h = 0, s_mv = 0, s_x = 0;
  #pragma unroll
  for (int i = 0; i < 6; ++i){
    int r = ln + 64 * i;
    float c_ = CCs[b * NH + r]; cc6[i] = c_; s_cc += (double)c_ * c_;
    float h_ = Hs[b * NH + r];  s_h += (double)h_ * h_;
    float m_ = zb[NG4 + r];     mv6[i] = m_; s_mv += (double)m_ * m_;
    float x_ = xin[((size_t)b * NS + t) * NH + r]; s_x += (double)x_ * x_;
  }
  double cc2 = wredsumd(s_cc);  double cn = normclip(cc2);
  double hn  = normclip(wredsumd(s_h));
  double mvn = normclip(wredsumd(s_mv));
  double xn  = normclip(wredsumd(s_x));

  // ---- c path: c_s1 = expmap0(tanh(logmap0(mobius_matvec(W_d, cc)))) ----
  double s1 = tanh(mvn / cn * artanh_(cn));
  float c1f = (float)(s1 / mvn);
  float m1[6]; double sm1 = 0;
  #pragma unroll
  for (int i = 0; i < 6; ++i){ m1[i] = c1f * mv6[i]; sm1 += (double)m1[i] * m1[i]; }
  double n1 = normclip(wredsumd(sm1));
  float l1f = (float)(artanh_(n1) / n1);
  float v6[6]; double sv = 0;
  #pragma unroll
  for (int i = 0; i < 6; ++i){ v6[i] = tanhf(l1f * m1[i]); sv += (double)v6[i] * v6[i]; }
  double nv = normclip(wredsumd(sv));
  float e1f = (float)(tanh(nv) / nv);
  float cs1[6]; double scs = 0, sccd = 0;
  #pragma unroll
  for (int i = 0; i < 6; ++i){ cs1[i] = e1f * v6[i]; scs += (double)cs1[i] * cs1[i]; sccd -= (double)cs1[i] * cc6[i]; }

  // c_s2 = mobius_pw(c_s1, t_s * ones)
  double xnt = sqrt(fmax(384.0 * ts * ts, 1e-15));
  double swx = 0;
  #pragma unroll
  for (int i = 0; i < 6; ++i){ float w = cs1[i] * tsf; swx += (double)w * w; }
  double wxn1 = normclip(wredsumd(swx));
  double s2c = tanh(wxn1 / xnt * artanh_(xnt)) / wxn1;
  float s2f = (float)(s2c * ts);
  float cs2[6];
  #pragma unroll
  for (int i = 0; i < 6; ++i) cs2[i] = s2f * cs1[i];

  // A = mobius_add(-c_s1, cc)
  double x2a = wredsumd(scs);
  double xya = wredsumd(sccd);
  double y2a = cc2;
  double dA = fmax(1.0 + 2.0 * xya + x2a * y2a, 1e-15);
  float fXA = (float)((1.0 + 2.0 * xya + y2a) / dA);
  float fYA = (float)((1.0 - x2a) / dA);
  float A6[6]; double sA = 0, sAc = 0, sc2 = 0;
  #pragma unroll
  for (int i = 0; i < 6; ++i){
    A6[i] = fXA * (-cs1[i]) + fYA * cc6[i];
    sA += (double)A6[i] * A6[i]; sAc += (double)A6[i] * cs2[i]; sc2 += (double)cs2[i] * cs2[i];
  }
  // c_adj = mobius_add(A, c_s2)
  double x2b = wredsumd(sA), xyb = wredsumd(sAc), y2b = wredsumd(sc2);
  double dB = fmax(1.0 + 2.0 * xyb + x2b * y2b, 1e-15);
  float fXB = (float)((1.0 + 2.0 * xyb + y2b) / dB);
  float fYB = (float)((1.0 - x2b) / dB);
  float cadj[6];
  #pragma unroll
  for (int i = 0; i < 6; ++i) cadj[i] = fXB * A6[i] + fYB * cs2[i];

  // ---- gates f,i,o,ct ----
  double art_hn = artanh_(hn), art_xn = artanh_(xn);
  float gates[4][6];
  for (int g = 0; g < 4; ++g){
    float pg[6], qg[6]; double s_p = 0, s_q = 0;
    #pragma unroll
    for (int i = 0; i < 6; ++i){
      int r = ln + 64 * i;
      pg[i] = zb[g * NH + r];       s_p += (double)pg[i] * pg[i];
      qg[i] = qb[g * NH + r];       s_q += (double)qg[i] * qg[i];
    }
    double pn = normclip(wredsumd(s_p));
    double qn = normclip(wredsumd(s_q));
    float saf = (float)(tanh(pn / hn * art_hn) / pn);
    float sbf = (float)(tanh(qn / xn * art_xn) / qn);
    float a6[6], b6[6]; double sx2 = 0, sy2 = 0, sxy = 0;
    #pragma unroll
    for (int i = 0; i < 6; ++i){
      a6[i] = saf * pg[i]; b6[i] = sbf * qg[i];
      sx2 += (double)a6[i] * a6[i]; sy2 += (double)b6[i] * b6[i]; sxy += (double)a6[i] * b6[i];
    }
    sx2 = wredsumd(sx2); sy2 = wredsumd(sy2); sxy = wredsumd(sxy);
    double dd = fmax(1.0 + 2.0 * sxy + sx2 * sy2, 1e-15);
    float fX = (float)((1.0 + 2.0 * sxy + sy2) / dd);
    float fY = (float)((1.0 - sx2) / dd);
    float m6[6]; double smm = 0;
    #pragma unroll
    for (int i = 0; i < 6; ++i){ m6[i] = fX * a6[i] + fY * b6[i]; smm += (double)m6[i] * m6[i]; }
    double nm = normclip(wredsumd(smm));
    float slf = (float)(artanh_(nm) / nm);
    #pragma unroll
    for (int i = 0; i < 6; ++i) gates[g][i] = 1.f / (1.f + expf(-slf * m6[i]));
  }

  // ---- cc_n = mobius_add(pw(i,ct), pw(f,c_adj)) ----
  double sct = 0, sict = 0; float wP[6];
  #pragma unroll
  for (int i = 0; i < 6; ++i){ float ct = gates[3][i]; sct += (double)ct * ct; wP[i] = gates[1][i] * ct; sict += (double)wP[i] * wP[i]; }
  double ctn = normclip(wredsumd(sct));
  double wPn = normclip(wredsumd(sict));
  float sPf = (float)(tanh(wPn / ctn * artanh_(ctn)) / wPn);
  float P6[6]; double sPP = 0;
  #pragma unroll
  for (int i = 0; i < 6; ++i){ P6[i] = sPf * wP[i]; sPP += (double)P6[i] * P6[i]; }
  double sca = 0, sfca = 0; float wQ[6];
  #pragma unroll
  for (int i = 0; i < 6; ++i){ sca += (double)cadj[i] * cadj[i]; wQ[i] = gates[0][i] * cadj[i]; sfca += (double)wQ[i] * wQ[i]; }
  double can = normclip(wredsumd(sca));
  double wQn = normclip(wredsumd(sfca));
  float sQf = (float)(tanh(wQn / can * artanh_(can)) / wQn);
  float Q6[6]; double sQQ = 0, sPQ = 0;
  #pragma unroll
  for (int i = 0; i < 6; ++i){ Q6[i] = sQf * wQ[i]; sQQ += (double)Q6[i] * Q6[i]; sPQ += (double)P6[i] * Q6[i]; }
  double x2c = wredsumd(sPP), y2c = wredsumd(sQQ), xyc = wredsumd(sPQ);
  double dC = fmax(1.0 + 2.0 * xyc + x2c * y2c, 1e-15);
  float fXC = (float)((1.0 + 2.0 * xyc + y2c) / dC);
  float fYC = (float)((1.0 - x2c) / dC);
  float ccn6[6], w6[6]; double sw_ = 0;
  #pragma unroll
  for (int i = 0; i < 6; ++i){ ccn6[i] = fXC * P6[i] + fYC * Q6[i]; w6[i] = tanhf(ccn6[i]); sw_ += (double)w6[i] * w6[i]; }
  double nw = normclip(wredsumd(sw_));
  float eef = (float)(tanh(nw) / nw);
  float e6[6], wH[6]; double se = 0, soe = 0;
  #pragma unroll
  for (int i = 0; i < 6; ++i){ e6[i] = eef * w6[i]; se += (double)e6[i] * e6[i]; wH[i] = gates[2][i] * e6[i]; soe += (double)wH[i] * wH[i]; }
  double en = normclip(wredsumd(se));
  double wHn = normclip(wredsumd(soe));
  float sHf = (float)(tanh(wHn / en * artanh_(en)) / wHn);
  #pragma unroll
  for (int i = 0; i < 6; ++i){
    int r = ln + 64 * i;
    CCs[b * NH + r] = ccn6[i];
    Hs[b * NH + r] = sHf * wH[i];
    ctx[((size_t)b * NS + t) * NH + r] = gates[2][i];
  }
}

// ---------------- block reduce helpers (256 threads / 4 waves), double ----------------
__device__ __forceinline__ double blocksumd(double v, double* red){
  v = wredsumd(v);
  __syncthreads();
  if ((threadIdx.x & 63) == 0) red[threadIdx.x >> 6] = v;
  __syncthreads();
  return red[0] + red[1] + red[2] + red[3];
}
__device__ __forceinline__ double blockmaxd(double v, double* red){
  #pragma unroll
  for (int off = 32; off; off >>= 1) v = fmax(v, __shfl_xor(v, off, 64));
  __syncthreads();
  if ((threadIdx.x & 63) == 0) red[threadIdx.x >> 6] = v;
  __syncthreads();
  return fmax(fmax(red[0], red[1]), fmax(red[2], red[3]));
}

// ---------------- query / scores / softmax / aw / bt (one block per b) ----------------
__global__ __launch_bounds__(256) void kattn1(const float* __restrict__ Hs,
    const float* __restrict__ Win, const float* __restrict__ ctx,
    const float* __restrict__ dt, const float* __restrict__ ab,
    double* __restrict__ query, double* __restrict__ aw, double* __restrict__ bt)
{
  int b = blockIdx.x; int tid = threadIdx.x;
  __shared__ double hL[NH], qL[NH], sc[NS];
  __shared__ double red[4];
  for (int r = tid; r < NH; r += 256) hL[r] = (double)Hs[b * NH + r];
  __syncthreads();
  for (int r = tid; r < NH; r += 256){
    double s = 0;
    const float* wr = Win + (size_t)r * NH;
    for (int c = 0; c < NH; ++c) s += hL[c] * (double)wr[c];
    qL[r] = s; query[b * NH + r] = s;
  }
  __syncthreads();
  int wv = tid >> 6, ln = tid & 63;
  for (int s_ = wv; s_ < NS; s_ += 4){
    const float* crow = ctx + ((size_t)b * NS + s_) * NH;
    double par = 0;
    #pragma unroll
    for (int i = 0; i < 6; ++i){ int d = ln + 64 * i; par += qL[d] * (double)crow[d]; }
    par = wredsumd(par);
    if (ln == 0) sc[s_] = par;
  }
  __syncthreads();
  double v0 = sc[tid];
  double v1 = (tid + 256 < NS) ? sc[tid + 256] : -1e300;
  double mx = blockmaxd(fmax(v0, v1), red);
  double e0 = exp(v0 - mx);
  double e1 = (tid + 256 < NS) ? exp(v1 - mx) : 0.0;
  double tot = blocksumd(e0 + e1, red);
  double a0 = e0 / tot, a1 = e1 / tot;
  double n = normclip(blocksumd(a0 * a0 + a1 * a1, red));
  double s1 = tanh(n) / n;
  double w0 = s1 * a0, w1 = s1 * a1;
  double pn = normclip(blocksumd(w0 * w0 + w1 * w1, red));
  if (pn > 0.999){ double f = 0.999 / pn; w0 *= f; w1 *= f; }
  aw[b * NS + tid] = w0;
  if (tid + 256 < NS) aw[b * NS + tid + 256] = w1;
  double abv = (double)ab[b];
  double b0 = exp(-abv * (double)dt[b * NS + tid]);
  double b1v = (tid + 256 < NS) ? exp(-abv * (double)dt[b * NS + tid + 256]) : 0.0;
  double nb = normclip(blocksumd(b0 * b0 + b1v * b1v, red));
  double sb = tanh(nb) / nb;
  double c0 = sb * b0, c1 = sb * b1v;
  double pnb = normclip(blocksumd(c0 * c0 + c1 * c1, red));
  if (pnb > 0.999){ double f = 0.999 / pnb; c0 *= f; c1 *= f; }
  bt[b * NS + tid] = c0;
  if (tid + 256 < NS) bt[b * NS + tid + 256] = c1;
}

// ---------------- hyperbolic attention mixing, one block per (b, 32 h-rows) ----------------
__global__ __launch_bounds__(256) void kmix(const float* __restrict__ ctx,
    const double* __restrict__ aw, const double* __restrict__ bt,
    const float* __restrict__ ae, double* __restrict__ nom, double* __restrict__ den)
{
  int b = blockIdx.y; int h0 = blockIdx.x * 32;
  __shared__ float T[32][385];
  int tid = threadIdx.x;
  for (int idx = tid; idx < NS * 32; idx += 256){
    int s = idx >> 5, hh = idx & 31;
    T[hh][s] = ctx[((size_t)b * NS + s) * NH + h0 + hh];
  }
  __syncthreads();
  int wv = tid >> 6, ln = tid & 63;
  double aev = (double)ae[b];
  double aw6[6], bt6[6]; double sbt = 0;
  #pragma unroll
  for (int i = 0; i < 6; ++i){
    aw6[i] = aw[b * NS + ln + 64 * i];
    bt6[i] = bt[b * NS + ln + 64 * i];
    sbt += bt6[i] * bt6[i];
  }
  double xnb = normclip(wredsumd(sbt));
  double art_xnb = artanh_(xnb);
  double denacc = 0.0;
  for (int k = 0; k < 8; ++k){
    int hh = wv * 8 + k;
    double v[6]; double sx = 0;
    #pragma unroll
    for (int i = 0; i < 6; ++i){ v[i] = (double)T[hh][ln + 64 * i]; sx += v[i] * v[i]; }
    double xnv = normclip(wredsumd(sx));
    double wx[6]; double swx = 0;
    #pragma unroll
    for (int i = 0; i < 6; ++i){ wx[i] = aw6[i] * v[i]; swx += wx[i] * wx[i]; }
    double wxn = normclip(wredsumd(swx));
    double s1 = tanh(wxn / xnv * artanh_(xnv)) / wxn;
    double mix[6]; double sm = 0;
    #pragma unroll
    for (int i = 0; i < 6; ++i){ mix[i] = s1 * wx[i]; sm += mix[i] * mix[i]; }
    double n1 = normclip(wredsumd(sm));
    if (n1 > 0.999){ double f = 0.999 / n1;
      #pragma unroll
      for (int i = 0; i < 6; ++i) mix[i] *= f; }
    double sm2 = 0;
    #pragma unroll
    for (int i = 0; i < 6; ++i) sm2 += mix[i] * mix[i];
    double xn2 = normclip(wredsumd(sm2));
    double wx2[6]; double sw2 = 0;
    #pragma unroll
    for (int i = 0; i < 6; ++i){ wx2[i] = aev * mix[i]; sw2 += wx2[i] * wx2[i]; }
    double wxn2 = normclip(wredsumd(sw2));
    double s2 = tanh(wxn2 / xn2 * artanh_(xn2)) / wxn2;
    double tmp[6]; double st = 0;
    #pragma unroll
    for (int i = 0; i < 6; ++i){ tmp[i] = s2 * wx2[i]; st += tmp[i] * tmp[i]; }
    double n2 = normclip(wredsumd(st));
    if (n2 > 0.999){ double f = 0.999 / n2;
      #pragma unroll
      for (int i = 0; i < 6; ++i) tmp[i] *= f; }
    double wx3[6]; double sw3 = 0;
    #pragma unroll
    for (int i = 0; i < 6; ++i){ wx3[i] = tmp[i] * bt6[i]; sw3 += wx3[i] * wx3[i]; }
    double wxn3 = normclip(wredsumd(sw3));
    double s3 = tanh(wxn3 / xnb * art_xnb) / wxn3;
    double t2[6]; double st2 = 0;
    #pragma unroll
    for (int i = 0; i < 6; ++i){ t2[i] = s3 * wx3[i]; st2 += t2[i] * t2[i]; }
    double n3 = normclip(wredsumd(st2));
    if (n3 > 0.999){ double f = 0.999 / n3;
      #pragma unroll
      for (int i = 0; i < 6; ++i) t2[i] *= f; }
    #pragma unroll
    for (int i = 0; i < 6; ++i) t2[i] = fmax(t2[i], 0.0);
    double sxx = 0, syy = 0, sxy = 0;
    #pragma unroll
    for (int i = 0; i < 6; ++i){ sxx += mix[i] * mix[i]; syy += t2[i] * t2[i]; sxy += mix[i] * t2[i]; }
    sxx = wredsumd(sxx); syy = wredsumd(syy); sxy = wredsumd(sxy);
    double dn = fmax(1.0 + 2.0 * sxy + sxx * syy, 1e-15);
    double ca = (1.0 + 2.0 * sxy + syy) / dn, cb = (1.0 - sxx) / dn;
    double m2[6]; double sm3 = 0;
    #pragma unroll
    for (int i = 0; i < 6; ++i){ m2[i] = ca * mix[i] + cb * t2[i]; sm3 += m2[i] * m2[i]; }
    double n4 = normclip(wredsumd(sm3));
    if (n4 > 0.999){ double f = 0.999 / n4;
      #pragma unroll
      for (int i = 0; i < 6; ++i) m2[i] *= f; }
    double snn = 0;
    #pragma unroll
    for (int i = 0; i < 6; ++i) snn += m2[i] * m2[i];
    snn = wredsumd(snn);
    double lam = 2.0 / fmax(1.0 - snn, 1e-15);
    #pragma unroll
    for (int i = 0; i < 6; ++i) atomicAdd(&nom[b * NS + ln + 64 * i], lam * m2[i]);
    if (ln == 0) denacc += lam - 1.0;
  }
  if (ln == 0) atomicAdd(&den[b], denacc);
}

// ---------------- midpoint + logmap0 + output head, one block per b ----------------
__global__ __launch_bounds__(256) void kfinal(const double* __restrict__ nom,
    const double* __restrict__ den, const double* __restrict__ query,
    const float* __restrict__ Wout, const float* __restrict__ W1,
    const float* __restrict__ b1, const float* __restrict__ W2,
    const float* __restrict__ b2, float* __restrict__ out)
{
  int b = blockIdx.x; int tid = threadIdx.x;
  __shared__ double comb[768];
  __shared__ double att[NH];
  __shared__ double x1[NH];
  __shared__ double red[4];
  double dnb = fmax(den[b], 1e-10);
  double u0 = nom[b * NS + tid] / dnb;
  double u1 = (tid + 256 < NS) ? nom[b * NS + tid + 256] / dnb : 0.0;
  double n = normclip(blocksumd(u0 * u0 + u1 * u1, red));
  double sf = tanh(0.5 * artanh_(n)) / n;
  double f0 = sf * u0, f1 = sf * u1;
  double n2 = normclip(blocksumd(f0 * f0 + f1 * f1, red));
  double sl = artanh_(n2) / n2;
  comb[tid] = sl * f0;
  if (tid + 256 < NS) comb[tid + 256] = sl * f1;
  for (int r = tid; r < NH; r += 256) comb[NH + r] = query[b * NH + r];
  __syncthreads();
  for (int r = tid; r < NH; r += 256){
    double s = 0;
    const float* wr = Wout + (size_t)r * 768;
    for (int c = 0; c < 768; ++c) s += comb[c] * (double)wr[c];
    att[r] = tanh(s);
  }
  __syncthreads();
  for (int r = tid; r < NH; r += 256){
    double s = (double)b1[r];
    const float* wr = W1 + (size_t)r * NH;
    for (int c = 0; c < NH; ++c) s += att[c] * (double)wr[c];
    x1[r] = fmax(s, 0.0);
  }
  __syncthreads();
  double p0 = 0, p1 = 0;
  for (int c = tid; c < NH; c += 256){ p0 += x1[c] * (double)W2[c]; p1 += x1[c] * (double)W2[NH + c]; }
  p0 = blocksumd(p0, red);
  p1 = blocksumd(p1, red);
  if (tid == 0){ out[b * 2 + 0] = (float)(p0 + (double)b2[0]); out[b * 2 + 1] = (float)(p1 + (double)b2[1]); }
}

extern "C" void kernel_launch(void* const* d_in, const int* in_sizes, int n_in,
                              void* d_out, int out_size, void* d_ws, size_t ws_size,
                              hipStream_t stream)
{
  const float* inputs  = (const float*)d_in[0];
  const float* tstamps = (const float*)d_in[1];
  const float* delta_t = (const float*)d_in[2];
  const float* W_all   = (const float*)d_in[3];
  const float* U_all   = (const float*)d_in[4];
  const float* W_d     = (const float*)d_in[5];
  const float* Win     = (const float*)d_in[6];
  const float* Wout    = (const float*)d_in[7];
  const float* ae      = (const float*)d_in[8];
  const float* ab      = (const float*)d_in[9];
  const float* W1      = (const float*)d_in[10];
  const float* b1      = (const float*)d_in[11];
  const float* W2      = (const float*)d_in[12];
  const float* b2      = (const float*)d_in[13];
  float* out = (float*)d_out;

  // double region (base 256B-aligned)
  double* wd = (double*)d_ws;
  size_t od = 0;
  double* NOMD  = wd + od; od += (size_t)NB * NS;     // 49152
  double* DEND  = wd + od; od += (size_t)NB;          // 128
  double* QUERY = wd + od; od += (size_t)NB * NH;
  double* AW    = wd + od; od += (size_t)NB * NS;
  double* BT    = wd + od; od += (size_t)NB * NS;
  float* wf = (float*)(wd + od);
  size_t of = 0;
  float* WT   = wf + of; of += (size_t)NH * NZCOL;    // 1,327,104
  float* Zb   = wf + of; of += (size_t)NB * NZCOL;    // 442,368
  float* Hs32 = wf + of; of += (size_t)NB * NH;       // 49,152
  float* CCs32= wf + of; of += (size_t)NB * NH;       // 49,152
  float* CTX  = wf + of; of += (size_t)NB * NS * NH;  // 18,874,368
  float* Qp   = wf + of;                              // optional 75,497,472

  size_t bytes_base = od * 8 + of * 4;
  size_t bytes_q = (size_t)NB * NS * 1536 * 4;        // 302 MB
  bool usePre = (ws_size >= bytes_base + bytes_q);

  // zero NOMD..DEND (doubles) and Hs32/CCs32 (floats)
  int nzd = NB * NS + NB;
  hipLaunchKernelGGL(kzerod, dim3((nzd + 255) / 256), dim3(256), 0, stream, NOMD, nzd);
  int nzf = NB * NH * 2;
  hipLaunchKernelGGL(kzerof, dim3((nzf + 255) / 256), dim3(256), 0, stream, Hs32, nzf);

  int nprep = NH * NZCOL;
  hipLaunchKernelGGL(kprep, dim3((nprep + 255) / 256), dim3(256), 0, stream,
                     W_all, W_d, U_all, WT);

  const float* qsrc;
  unsigned long long q_bs, q_ts;
  int ncols, zstride;
  if (usePre){
    hipLaunchKernelGGL(kqgemm, dim3(24, 768), dim3(256), 0, stream, inputs, WT + 1920, Qp);
    qsrc = Qp; q_bs = (unsigned long long)NS * 1536ull; q_ts = 1536ull;
    ncols = 1920; zstride = 1920;
  } else {
    qsrc = Zb + 1920; q_bs = (unsigned long long)NZCOL; q_ts = 0ull;
    ncols = NZCOL; zstride = NZCOL;
  }

  for (int t = 0; t < NS; ++t){
    hipLaunchKernelGGL(kgemm, dim3(ncols / 64, 4), dim3(256), 0, stream,
                       WT, Hs32, CCs32, inputs, Zb, zstride, t);
    hipLaunchKernelGGL(knl, dim3(32), dim3(256), 0, stream,
                       Zb, zstride, qsrc, q_bs, q_ts, Hs32, CCs32, CTX, inputs, tstamps, t);
  }

  hipLaunchKernelGGL(kattn1, dim3(128), dim3(256), 0, stream,
                     Hs32, Win, CTX, delta_t, ab, QUERY, AW, BT);
  hipLaunchKernelGGL(kmix, dim3(12, 128), dim3(256), 0, stream, CTX, AW, BT, ae, NOMD, DEND);
  hipLaunchKernelGGL(kfinal, dim3(128), dim3(256), 0, stream,
                     NOMD, DEND, QUERY, Wout, W1, b1, W2, b2, out);
}